// Round 4
// baseline (1166.239 us; speedup 1.0000x reference)
//
#include <hip/hip_runtime.h>
#include <hip/hip_cooperative_groups.h>
#include <stdint.h>

namespace cg = cooperative_groups;

#define NN 2048
#define FF 64
#define NB 32

typedef __attribute__((ext_vector_type(8))) short bf16x8;
typedef __attribute__((ext_vector_type(4))) float f32x4;

__device__ __forceinline__ uint16_t f2bf(float f) {
  uint32_t u = __builtin_bit_cast(uint32_t, f);
  return (uint16_t)((u + 0x7FFFu + ((u >> 16) & 1u)) >> 16);  // RNE truncation
}
__device__ __forceinline__ float bf2f(uint16_t h) {
  uint32_t u = ((uint32_t)h) << 16;
  return __builtin_bit_cast(float, u);
}

// ---------------- W [64(k)][64(f)] fp32 -> Wt [64(f)][64(k)] bf16 ----------------
__global__ void k_prep(const float* __restrict__ W, uint16_t* __restrict__ Wt) {
  int t = threadIdx.x;  // 256
  for (int i = 0; i < 16; ++i) {
    int idx = t * 16 + i;  // = k*64 + f
    int k = idx >> 6, f = idx & 63;
    Wt[f * 64 + k] = f2bf(W[idx]);
  }
}

// ---------------- phase A: xw = x @ W, writes [b][n][f] and [b][f][n] ------------
__device__ __forceinline__ void phaseA(const float* __restrict__ x,
                                       const uint16_t* __restrict__ Wt,
                                       uint16_t* __restrict__ xw,
                                       uint16_t* __restrict__ xwT,
                                       short* As) {
  int bid = blockIdx.x;
  int b = bid >> 5;
  int n0 = (bid & 31) * 64;
  int t = threadIdx.x;
  const float* xb = x + ((size_t)b * NN + n0) * FF;
  for (int i = 0; i < 4; ++i) {
    int idx = t + i * 256;  // 1024 float4 chunks
    int r = idx >> 4, c = (idx & 15) * 4;
    float4 v = *(const float4*)(xb + r * FF + c);
    uint32_t p0 = f2bf(v.x) | ((uint32_t)f2bf(v.y) << 16);
    uint32_t p1 = f2bf(v.z) | ((uint32_t)f2bf(v.w) << 16);
    uint2 pv = {p0, p1};
    *(uint2*)&As[r * 72 + c] = pv;
  }
  __syncthreads();
  int lane = t & 63, wave = t >> 6;
  int l16 = lane & 15, quad = lane >> 4;
  f32x4 acc[4] = {};
  for (int ks = 0; ks < 2; ++ks) {
    bf16x8 a = *(const bf16x8*)&As[(wave * 16 + l16) * 72 + ks * 32 + quad * 8];
    for (int fi = 0; fi < 4; ++fi) {
      bf16x8 bq = *(const bf16x8*)(Wt + (fi * 16 + l16) * 64 + ks * 32 + quad * 8);
      acc[fi] = __builtin_amdgcn_mfma_f32_16x16x32_bf16(a, bq, acc[fi], 0, 0, 0);
    }
  }
  for (int fi = 0; fi < 4; ++fi)
    for (int r = 0; r < 4; ++r) {
      int n = n0 + wave * 16 + quad * 4 + r;
      int f = fi * 16 + l16;
      xw[((size_t)b * NN + n) * FF + f] = f2bf(acc[fi][r]);
    }
  __syncthreads();  // done reading As as x-tile
  uint16_t* T = (uint16_t*)As;
  for (int fi = 0; fi < 4; ++fi)
    for (int r = 0; r < 4; ++r)
      T[(fi * 16 + l16) * 72 + wave * 16 + quad * 4 + r] = f2bf(acc[fi][r]);
  __syncthreads();
  int f = t >> 2, seg = t & 3;
  uint4 v0 = *(const uint4*)&T[f * 72 + seg * 16];
  uint4 v1 = *(const uint4*)&T[f * 72 + seg * 16 + 8];
  uint16_t* dp = xwT + ((size_t)b * FF + f) * NN + n0 + seg * 16;
  *(uint4*)dp = v0;
  *(uint4*)(dp + 8) = v1;
}

// ---------------- phase G: Y = A @ X (identical math to verified R3 k_gemm) ------
__device__ __forceinline__ void phaseG(int EPI,
                                       const float* __restrict__ adj,
                                       const uint16_t* __restrict__ Bt,
                                       uint16_t* __restrict__ Yb,
                                       uint16_t* __restrict__ YbT,
                                       const uint16_t* __restrict__ xw,
                                       const uint16_t* __restrict__ y1,
                                       const float* __restrict__ Kc,
                                       const float* __restrict__ bias,
                                       float* __restrict__ out,
                                       short (*As)[64 * 72], short (*Bs)[64 * 72]) {
  int bid = blockIdx.x;
  int b = bid & 31;   // batch pinned to XCD b%8 -> B-tile L2 reuse
  int rt = bid >> 5;  // 32 row-tiles of 64
  int row0 = rt << 6;
  int t = threadIdx.x;
  int lane = t & 63, wave = t >> 6;
  int l16 = lane & 15, quad = lane >> 4;
  int krot = ((b * 11) + rt * 7) & 31;
  const float* Ab = adj + (size_t)b * NN * NN + (size_t)row0 * NN;
  const uint16_t* Btb = Bt + (size_t)b * FF * NN;

  int ra[4], ca[4];
  for (int i = 0; i < 4; ++i) {
    int chunk = t + i * 256;
    ra[i] = chunk >> 4;
    ca[i] = (chunk & 15) * 4;
  }
  int fb[2], kb8[2];
  for (int j = 0; j < 2; ++j) {
    int chunk = t + j * 256;
    fb[j] = chunk >> 3;
    kb8[j] = (chunk & 7) * 8;
  }

  float4 areg[4];
  uint4 breg[2];
  {
    int kn = krot * 64;
    for (int i = 0; i < 4; ++i)
      areg[i] = *(const float4*)(Ab + (size_t)ra[i] * NN + kn + ca[i]);
    for (int j = 0; j < 2; ++j)
      breg[j] = *(const uint4*)(Btb + (size_t)fb[j] * NN + kn + kb8[j]);
  }

  f32x4 acc[4] = {};
  for (int it = 0; it < 32; ++it) {
    asm volatile("s_waitcnt vmcnt(0)" ::: "memory");
    int p = it & 1;
    for (int i = 0; i < 4; ++i) {
      float4 v = areg[i];
      uint32_t p0 = f2bf(v.x) | ((uint32_t)f2bf(v.y) << 16);
      uint32_t p1 = f2bf(v.z) | ((uint32_t)f2bf(v.w) << 16);
      uint2 pv = {p0, p1};
      *(uint2*)&As[p][ra[i] * 72 + ca[i]] = pv;
    }
    for (int j = 0; j < 2; ++j)
      *(uint4*)&Bs[p][fb[j] * 72 + kb8[j]] = breg[j];
    if (it + 1 < 32) {
      int kn = ((krot + it + 1) & 31) * 64;
      for (int i = 0; i < 4; ++i)
        areg[i] = *(const float4*)(Ab + (size_t)ra[i] * NN + kn + ca[i]);
      for (int j = 0; j < 2; ++j)
        breg[j] = *(const uint4*)(Btb + (size_t)fb[j] * NN + kn + kb8[j]);
    }
    asm volatile("s_waitcnt lgkmcnt(0)" ::: "memory");
    __builtin_amdgcn_s_barrier();
    for (int ks = 0; ks < 2; ++ks) {
      bf16x8 a = *(const bf16x8*)&As[p][(wave * 16 + l16) * 72 + ks * 32 + quad * 8];
      for (int fi = 0; fi < 4; ++fi) {
        bf16x8 bq = *(const bf16x8*)&Bs[p][(fi * 16 + l16) * 72 + ks * 32 + quad * 8];
        acc[fi] = __builtin_amdgcn_mfma_f32_16x16x32_bf16(a, bq, acc[fi], 0, 0, 0);
      }
    }
  }

  if (EPI == 0) {
    for (int fi = 0; fi < 4; ++fi)
      for (int r = 0; r < 4; ++r) {
        int n = row0 + wave * 16 + quad * 4 + r;
        int f = fi * 16 + l16;
        Yb[((size_t)b * NN + n) * FF + f] = f2bf(acc[fi][r]);
      }
    __syncthreads();
    uint16_t* T = (uint16_t*)&As[0][0];
    for (int fi = 0; fi < 4; ++fi)
      for (int r = 0; r < 4; ++r)
        T[(fi * 16 + l16) * 72 + wave * 16 + quad * 4 + r] = f2bf(acc[fi][r]);
    __syncthreads();
    int f = t >> 2, seg = t & 3;
    uint4 v0 = *(const uint4*)&T[f * 72 + seg * 16];
    uint4 v1 = *(const uint4*)&T[f * 72 + seg * 16 + 8];
    uint16_t* dp = YbT + ((size_t)b * FF + f) * NN + row0 + seg * 16;
    *(uint4*)dp = v0;
    *(uint4*)(dp + 8) = v1;
  } else {
    float ka = Kc[0] - Kc[2], kb = Kc[1], kc = 2.0f * Kc[2];
    for (int fi = 0; fi < 4; ++fi) {
      int f = fi * 16 + l16;
      float bv = bias[f];
      for (int r = 0; r < 4; ++r) {
        int n = row0 + wave * 16 + quad * 4 + r;
        size_t idx = ((size_t)b * NN + n) * FF + f;
        out[idx] = ka * bf2f(xw[idx]) + kb * bf2f(y1[idx]) + kc * acc[fi][r] + bv;
      }
    }
  }
}

// ---------------- fused cooperative pipeline: A -> sync -> G0 -> sync -> G1 ------
__global__ __launch_bounds__(256, 4) void k_fused(
    const float* __restrict__ x, const float* __restrict__ adj,
    const uint16_t* __restrict__ Wt, const float* __restrict__ Kc,
    const float* __restrict__ bias, float* __restrict__ out,
    uint16_t* __restrict__ xw, uint16_t* __restrict__ xwT,
    uint16_t* __restrict__ y1, uint16_t* __restrict__ y1T) {
  __shared__ short As[2][64 * 72];  // 18 KiB
  __shared__ short Bs[2][64 * 72];  // 18 KiB  -> 36 KiB total, 4 blocks/CU
  cg::grid_group grid = cg::this_grid();
  phaseA(x, Wt, xw, xwT, &As[0][0]);
  grid.sync();
  phaseG(0, adj, xwT, y1, y1T, nullptr, nullptr, nullptr, nullptr, nullptr, As, Bs);
  grid.sync();
  phaseG(1, adj, y1T, nullptr, nullptr, xw, y1, Kc, bias, out, As, Bs);
}

// =================== fallback path (verified R3 kernels) =========================
__global__ __launch_bounds__(256) void k_xw(const float* __restrict__ x,
                                            const uint16_t* __restrict__ Wt,
                                            uint16_t* __restrict__ xw,
                                            uint16_t* __restrict__ xwT) {
  __shared__ short As[64 * 72];
  phaseA(x, Wt, xw, xwT, As);
}

template <int EPI>
__global__ __launch_bounds__(256, 4) void k_gemm(const float* __restrict__ adj,
                                                 const uint16_t* __restrict__ Bt,
                                                 uint16_t* __restrict__ Yb,
                                                 uint16_t* __restrict__ YbT,
                                                 const uint16_t* __restrict__ xw,
                                                 const uint16_t* __restrict__ y1,
                                                 const float* __restrict__ Kc,
                                                 const float* __restrict__ bias,
                                                 float* __restrict__ out) {
  __shared__ short As[2][64 * 72];
  __shared__ short Bs[2][64 * 72];
  phaseG(EPI, adj, Bt, Yb, YbT, xw, y1, Kc, bias, out, As, Bs);
}

extern "C" void kernel_launch(void* const* d_in, const int* in_sizes, int n_in,
                              void* d_out, int out_size, void* d_ws, size_t ws_size,
                              hipStream_t stream) {
  const float* x    = (const float*)d_in[0];
  const float* adj  = (const float*)d_in[1];
  const float* W    = (const float*)d_in[2];
  const float* K    = (const float*)d_in[3];
  const float* bias = (const float*)d_in[4];
  float* out = (float*)d_out;

  uint8_t* ws = (uint8_t*)d_ws;
  const size_t SZ = (size_t)NB * NN * FF * sizeof(uint16_t);  // 8 MiB per buffer
  uint16_t* xw_n = (uint16_t*)(ws);
  uint16_t* xwT  = (uint16_t*)(ws + SZ);
  uint16_t* y1_n = (uint16_t*)(ws + 2 * SZ);
  uint16_t* y1T  = (uint16_t*)(ws + 3 * SZ);
  uint16_t* Wt   = (uint16_t*)(ws + 4 * SZ);

  k_prep<<<dim3(1), dim3(256), 0, stream>>>(W, Wt);

  void* args[] = {(void*)&x,   (void*)&adj,  (void*)&Wt,   (void*)&K,
                  (void*)&bias, (void*)&out, (void*)&xw_n, (void*)&xwT,
                  (void*)&y1_n, (void*)&y1T};
  hipError_t err = hipLaunchCooperativeKernel((const void*)k_fused, dim3(1024),
                                              dim3(256), args, 0, stream);
  if (err != hipSuccess) {
    // fallback: verified multi-kernel pipeline
    k_xw<<<dim3(1024), dim3(256), 0, stream>>>(x, Wt, xw_n, xwT);
    k_gemm<0><<<dim3(1024), dim3(256), 0, stream>>>(adj, xwT, y1_n, y1T, nullptr,
                                                    nullptr, nullptr, nullptr, nullptr);
    k_gemm<1><<<dim3(1024), dim3(256), 0, stream>>>(adj, y1T, nullptr, nullptr, xw_n,
                                                    y1_n, K, bias, out);
  }
}

// Round 5
// 946.939 us; speedup vs baseline: 1.2316x; 1.2316x over previous
//
#include <hip/hip_runtime.h>
#include <hip/hip_cooperative_groups.h>
#include <stdint.h>

namespace cg = cooperative_groups;

#define NN 2048
#define FF 64
#define NB 32

#define A_TILE 16384              // 64 rows x 64 k fp32
#define B_TILE 8192               // 64 f x 64 k bf16 (swizzled image)
#define SLOT (A_TILE + B_TILE)    // 24576
#define LDS_BYTES (3 * SLOT)      // 73728

typedef __attribute__((ext_vector_type(8))) short bf16x8;
typedef __attribute__((ext_vector_type(4))) float f32x4;

__device__ __forceinline__ uint16_t f2bf(float f) {
  uint32_t u = __builtin_bit_cast(uint32_t, f);
  return (uint16_t)((u + 0x7FFFu + ((u >> 16) & 1u)) >> 16);  // RNE truncation
}
__device__ __forceinline__ float bf2f(uint16_t h) {
  uint32_t u = ((uint32_t)h) << 16;
  return __builtin_bit_cast(float, u);
}
// async global->LDS: dest = wave-uniform base (+ lane*16 by HW); src is PER-LANE.
__device__ __forceinline__ void gll16(const void* g, void* l) {
  __builtin_amdgcn_global_load_lds(
      (const __attribute__((address_space(1))) void*)g,
      (__attribute__((address_space(3))) void*)l, 16, 0, 0);
}

// ---------------- W [64(k)][64(f)] fp32 -> Wt [64(f)][64(k)] bf16 ----------------
__global__ void k_prep(const float* __restrict__ W, uint16_t* __restrict__ Wt) {
  int t = threadIdx.x;  // 256
  for (int i = 0; i < 16; ++i) {
    int idx = t * 16 + i;  // = k*64 + f
    int k = idx >> 6, f = idx & 63;
    Wt[f * 64 + k] = f2bf(W[idx]);
  }
}

// ------- phase A: xw = x @ W; writes xw [b][n][f] + xwT blocked-SWIZZLED tiles ---
// Bt tile format (8 KB, per [b][kt]): byte off(f, c) = f*128 + (c ^ ((f&7)<<4)),
// c = 2*k_local. Tiles are the exact LDS image the gemm wants -> gll16 is linear.
__device__ __forceinline__ void phaseAF(const float* __restrict__ x,
                                        const uint16_t* __restrict__ Wt,
                                        uint16_t* __restrict__ xw,
                                        char* __restrict__ xwT, char* LDS) {
  int bid = blockIdx.x;  // 512
  int b = bid & 31, rp = bid >> 5;
  int t = threadIdx.x;
  int lane = t & 63, wave = t >> 6, l16 = lane & 15, quad = lane >> 4;
  short* As = (short*)LDS;  // 64*72 bf16
  for (int h = 0; h < 2; ++h) {
    int tile = rp * 2 + h;
    int n0 = tile * 64;
    const float* xb = x + ((size_t)b * NN + n0) * FF;
    for (int i = 0; i < 4; ++i) {
      int idx = t + i * 256;  // 1024 float4
      int r = idx >> 4, c = (idx & 15) * 4;
      float4 v = *(const float4*)(xb + r * FF + c);
      uint32_t p0 = f2bf(v.x) | ((uint32_t)f2bf(v.y) << 16);
      uint32_t p1 = f2bf(v.z) | ((uint32_t)f2bf(v.w) << 16);
      uint2 pv = {p0, p1};
      *(uint2*)&As[r * 72 + c] = pv;
    }
    __syncthreads();
    f32x4 acc[4] = {};
    for (int ks = 0; ks < 2; ++ks) {
      bf16x8 a = *(const bf16x8*)&As[(wave * 16 + l16) * 72 + ks * 32 + quad * 8];
      for (int fi = 0; fi < 4; ++fi) {
        bf16x8 bq = *(const bf16x8*)(Wt + (fi * 16 + l16) * 64 + ks * 32 + quad * 8);
        acc[fi] = __builtin_amdgcn_mfma_f32_16x16x32_bf16(a, bq, acc[fi], 0, 0, 0);
      }
    }
    for (int fi = 0; fi < 4; ++fi)
      for (int r = 0; r < 4; ++r) {
        int n = n0 + wave * 16 + quad * 4 + r;
        int f = fi * 16 + l16;
        xw[((size_t)b * NN + n) * FF + f] = f2bf(acc[fi][r]);
      }
    __syncthreads();  // done reading As
    uint16_t* T = (uint16_t*)LDS;
    for (int fi = 0; fi < 4; ++fi)
      for (int r = 0; r < 4; ++r)
        T[(fi * 16 + l16) * 72 + wave * 16 + quad * 4 + r] = f2bf(acc[fi][r]);
    __syncthreads();
    {
      int f = t >> 2, seg = t & 3;
      uint4 v0 = *(const uint4*)&T[f * 72 + seg * 16];
      uint4 v1 = *(const uint4*)&T[f * 72 + seg * 16 + 8];
      char* tb = xwT + ((size_t)b * 32 + tile) * B_TILE + f * 128;
      int sw = (f & 7) << 4;
      *(uint4*)(tb + ((seg * 32) ^ sw)) = v0;
      *(uint4*)(tb + ((seg * 32 + 16) ^ sw)) = v1;
    }
    __syncthreads();  // T free before next half
  }
}

// ---------------- gemm tile staging: A per-lane-swizzled src, B linear -----------
__device__ __forceinline__ void stage_tile(const float* __restrict__ Ab,
                                           const char* __restrict__ btiles, int kt,
                                           char* Abuf, int wave, int lane) {
  char* Bbuf = Abuf + A_TILE;
  int cp = (lane & 15) * 16;
  for (int j = 0; j < 4; ++j) {
    int row = wave * 16 + j * 4 + (lane >> 4);
    const char* src =
        (const char*)(Ab + (size_t)row * NN + kt * 64) + (cp ^ ((row & 7) << 4));
    gll16(src, Abuf + (wave * 4 + j) * 1024);
  }
  const char* bt = btiles + (size_t)kt * B_TILE;
  for (int j = 0; j < 2; ++j)
    gll16(bt + (wave * 2 + j) * 1024 + lane * 16, Bbuf + (wave * 2 + j) * 1024);
}

// ---------------- phase G: Y = A @ X, counted-vmcnt triple-buffer pipeline -------
// EPI=0: Yb linear bf16 + YbT blocked-swizzled tiles. EPI=1: final combine fp32.
template <int EPI>
__device__ __forceinline__ void phaseGF(const float* __restrict__ adj,
                                        const char* __restrict__ BtT,
                                        uint16_t* __restrict__ Yb,
                                        char* __restrict__ YbT,
                                        const uint16_t* __restrict__ xw,
                                        const uint16_t* __restrict__ y1,
                                        const float* __restrict__ Kc,
                                        const float* __restrict__ bias,
                                        float* __restrict__ out, char* LDS) {
  int bid = blockIdx.x;  // 512
  int b = bid & 31, rp = bid >> 5;
  int t = threadIdx.x;
  int lane = t & 63, wave = t >> 6, l16 = lane & 15, quad = lane >> 4;
  const char* btiles = BtT + (size_t)b * 32 * B_TILE;
  int krot = ((b * 11) + rp * 7) & 31;  // spread DRAM pages (R1: +65us, keep)

  for (int h = 0; h < 2; ++h) {
    int rt = rp * 2 + h;
    int row0 = rt << 6;
    const float* Ab = adj + ((size_t)b * NN + row0) * NN;

    // prologue: tiles g(0)->slot0, g(1)->slot1 (12 gll16 in flight)
    for (int pp = 0; pp < 2; ++pp)
      stage_tile(Ab, btiles, (krot + pp) & 31, LDS + pp * SLOT, wave, lane);

    f32x4 acc[4] = {};
    for (int it = 0; it < 32; ++it) {
      // counted wait: tile it landed; tile it+1's 6 loads STAY IN FLIGHT.
      if (it < 31) asm volatile("s_waitcnt vmcnt(6)" ::: "memory");
      else         asm volatile("s_waitcnt vmcnt(0)" ::: "memory");
      __builtin_amdgcn_s_barrier();  // collective: whole tile it visible
      if (it + 2 < 32)               // 2-deep: issue tile it+2 (never drain to 0)
        stage_tile(Ab, btiles, (krot + it + 2) & 31, LDS + ((it + 2) % 3) * SLOT,
                   wave, lane);
      const char* Abuf = LDS + (it % 3) * SLOT;
      const char* Bbuf = Abuf + A_TILE;
      int arow = wave * 16 + l16;
      const char* abase = Abuf + arow * 256;
      int asw = (arow & 7) << 4;
      for (int ks = 0; ks < 2; ++ks) {
        int c0 = ks * 128 + quad * 32;
        f32x4 lo = *(const f32x4*)(abase + (c0 ^ asw));
        f32x4 hi = *(const f32x4*)(abase + ((c0 + 16) ^ asw));
        union { bf16x8 v; uint32_t u[4]; } au;
        au.u[0] = f2bf(lo[0]) | ((uint32_t)f2bf(lo[1]) << 16);
        au.u[1] = f2bf(lo[2]) | ((uint32_t)f2bf(lo[3]) << 16);
        au.u[2] = f2bf(hi[0]) | ((uint32_t)f2bf(hi[1]) << 16);
        au.u[3] = f2bf(hi[2]) | ((uint32_t)f2bf(hi[3]) << 16);
        for (int fi = 0; fi < 4; ++fi) {
          int fr = fi * 16 + l16;
          bf16x8 bq = *(const bf16x8*)(Bbuf + fr * 128 +
                                       ((ks * 64 + quad * 16) ^ ((fr & 7) << 4)));
          acc[fi] = __builtin_amdgcn_mfma_f32_16x16x32_bf16(au.v, bq, acc[fi], 0, 0, 0);
        }
      }
    }

    if (EPI == 0) {
      for (int fi = 0; fi < 4; ++fi)
        for (int r = 0; r < 4; ++r) {
          int n = row0 + wave * 16 + quad * 4 + r;
          int f = fi * 16 + l16;
          Yb[((size_t)b * NN + n) * FF + f] = f2bf(acc[fi][r]);
        }
      __syncthreads();  // all waves past compute (slot2); T uses slot0 area
      uint16_t* T = (uint16_t*)LDS;
      for (int fi = 0; fi < 4; ++fi)
        for (int r = 0; r < 4; ++r)
          T[(fi * 16 + l16) * 72 + wave * 16 + quad * 4 + r] = f2bf(acc[fi][r]);
      __syncthreads();
      {
        int f = t >> 2, seg = t & 3;
        uint4 v0 = *(const uint4*)&T[f * 72 + seg * 16];
        uint4 v1 = *(const uint4*)&T[f * 72 + seg * 16 + 8];
        char* tb = YbT + ((size_t)b * 32 + rt) * B_TILE + f * 128;
        int sw = (f & 7) << 4;
        *(uint4*)(tb + ((seg * 32) ^ sw)) = v0;
        *(uint4*)(tb + ((seg * 32 + 16) ^ sw)) = v1;
      }
      __syncthreads();  // T free before next-half prologue overwrites slot0
    } else {
      float ka = Kc[0] - Kc[2], kb = Kc[1], kc = 2.0f * Kc[2];
      for (int fi = 0; fi < 4; ++fi) {
        int f = fi * 16 + l16;
        float bv = bias[f];
        for (int r = 0; r < 4; ++r) {
          int n = row0 + wave * 16 + quad * 4 + r;
          size_t idx = ((size_t)b * NN + n) * FF + f;
          out[idx] = ka * bf2f(xw[idx]) + kb * bf2f(y1[idx]) + kc * acc[fi][r] + bv;
        }
      }
    }
  }
}

// ---------------- fused cooperative pipeline ------------------------------------
__global__ __launch_bounds__(256, 2) void k_fused(
    const float* __restrict__ x, const float* __restrict__ adj,
    const uint16_t* __restrict__ Wt, const float* __restrict__ Kc,
    const float* __restrict__ bias, float* __restrict__ out,
    uint16_t* __restrict__ xw, char* __restrict__ xwT,
    uint16_t* __restrict__ y1, char* __restrict__ y1T) {
  __shared__ __align__(16) char LDS[LDS_BYTES];  // 72 KiB -> 2 blocks/CU, grid 512
  cg::grid_group grid = cg::this_grid();
  phaseAF(x, Wt, xw, xwT, LDS);
  grid.sync();
  phaseGF<0>(adj, xwT, y1, y1T, nullptr, nullptr, nullptr, nullptr, nullptr, LDS);
  grid.sync();
  phaseGF<1>(adj, y1T, nullptr, nullptr, xw, y1, Kc, bias, out, LDS);
}

// =================== fallback multi-kernel path ==================================
__global__ __launch_bounds__(256) void k_xwF(const float* __restrict__ x,
                                             const uint16_t* __restrict__ Wt,
                                             uint16_t* __restrict__ xw,
                                             char* __restrict__ xwT) {
  __shared__ __align__(16) char LDS[64 * 72 * 2];
  phaseAF(x, Wt, xw, xwT, LDS);
}

template <int EPI>
__global__ __launch_bounds__(256, 2) void k_gemmF(const float* __restrict__ adj,
                                                  const char* __restrict__ BtT,
                                                  uint16_t* __restrict__ Yb,
                                                  char* __restrict__ YbT,
                                                  const uint16_t* __restrict__ xw,
                                                  const uint16_t* __restrict__ y1,
                                                  const float* __restrict__ Kc,
                                                  const float* __restrict__ bias,
                                                  float* __restrict__ out) {
  __shared__ __align__(16) char LDS[LDS_BYTES];
  phaseGF<EPI>(adj, BtT, Yb, YbT, xw, y1, Kc, bias, out, LDS);
}

extern "C" void kernel_launch(void* const* d_in, const int* in_sizes, int n_in,
                              void* d_out, int out_size, void* d_ws, size_t ws_size,
                              hipStream_t stream) {
  const float* x    = (const float*)d_in[0];
  const float* adj  = (const float*)d_in[1];
  const float* W    = (const float*)d_in[2];
  const float* K    = (const float*)d_in[3];
  const float* bias = (const float*)d_in[4];
  float* out = (float*)d_out;

  uint8_t* ws = (uint8_t*)d_ws;
  const size_t SZ = (size_t)NB * NN * FF * sizeof(uint16_t);  // 8 MiB per buffer
  uint16_t* xw_n = (uint16_t*)(ws);
  char*     xwT  = (char*)(ws + SZ);
  uint16_t* y1_n = (uint16_t*)(ws + 2 * SZ);
  char*     y1T  = (char*)(ws + 3 * SZ);
  uint16_t* Wt   = (uint16_t*)(ws + 4 * SZ);

  k_prep<<<dim3(1), dim3(256), 0, stream>>>(W, Wt);

  void* args[] = {(void*)&x,    (void*)&adj, (void*)&Wt,   (void*)&K,
                  (void*)&bias, (void*)&out, (void*)&xw_n, (void*)&xwT,
                  (void*)&y1_n, (void*)&y1T};
  hipError_t err = hipLaunchCooperativeKernel((const void*)k_fused, dim3(512),
                                              dim3(256), args, 0, stream);
  if (err != hipSuccess) {
    k_xwF<<<dim3(512), dim3(256), 0, stream>>>(x, Wt, xw_n, xwT);
    k_gemmF<0><<<dim3(512), dim3(256), 0, stream>>>(adj, xwT, y1_n, y1T, nullptr,
                                                    nullptr, nullptr, nullptr, nullptr);
    k_gemmF<1><<<dim3(512), dim3(256), 0, stream>>>(adj, y1T, nullptr, nullptr, xw_n,
                                                    y1_n, K, bias, out);
  }
}